// Round 21
// baseline (546887.451 us; speedup 1.0000x reference)
//
#include <hip/hip_runtime.h>
#include <hip/hip_bf16.h>
#include <stdint.h>

#define B_    64
#define T_    512
#define H_    512
#define G_    2048    // 4*H
#define TAGS_ 20

typedef __hip_bfloat16 bf16;
typedef __bf16 bf16x8 __attribute__((ext_vector_type(8)));
typedef float  f32x4  __attribute__((ext_vector_type(4)));
typedef unsigned int u32;
typedef u32 u32x4 __attribute__((ext_vector_type(4)));
typedef u32 u32x2 __attribute__((ext_vector_type(2)));

__device__ __forceinline__ float sigmoidf_(float x) { return 1.0f / (1.0f + __expf(-x)); }
__device__ __forceinline__ float tanhf_(float x)    { return 1.0f - 2.0f / (__expf(2.0f * x) + 1.0f); }

// ---------------- prep kernels ----------------

__global__ void k_zero(uint32_t* __restrict__ p, int n) {
    for (int i = blockIdx.x * blockDim.x + threadIdx.x; i < n; i += gridDim.x * blockDim.x)
        p[i] = 0u;
}

__global__ void k_addb(const float* __restrict__ a, const float* __restrict__ b,
                       float* __restrict__ o, int n) {
    for (int i = blockIdx.x * blockDim.x + threadIdx.x; i < n; i += gridDim.x * blockDim.x)
        o[i] = a[i] + b[i];
}

__global__ __launch_bounds__(256) void k_lens(const int* __restrict__ x, int* __restrict__ lens) {
    int b = blockIdx.x;
    int cnt = 0;
    for (int tpos = threadIdx.x; tpos < T_; tpos += 256)
        cnt += (x[(size_t)b * T_ + tpos] == 0) ? 1 : 0;
    #pragma unroll
    for (int off = 32; off; off >>= 1) cnt += __shfl_xor(cnt, off);
    __shared__ int tot;
    if (threadIdx.x == 0) tot = 0;
    __syncthreads();
    if ((threadIdx.x & 63) == 0) atomicAdd(&tot, cnt);
    __syncthreads();
    if (threadIdx.x == 0) lens[b] = T_ - tot;
}

// E packed fragment-linear: Epk[(t*4+m)*16KB + f*1024 + lane*16] =
//   bf16x8 of emb[x[m*16+(lane&15)][t]][f*32+(lane>>4)*8 .. +8]
__global__ __launch_bounds__(256) void k_gather(const int* __restrict__ x,
                                                const float* __restrict__ emb,
                                                char* __restrict__ Epk) {
    const int t = blockIdx.x, m = blockIdx.y;
    __shared__ int tok[16];
    if (threadIdx.x < 16) tok[threadIdx.x] = x[(size_t)(m * 16 + threadIdx.x) * T_ + t];
    __syncthreads();
    char* base = Epk + ((size_t)(t * 4 + m)) * 16384;
    for (int task = threadIdx.x; task < 1024; task += 256) {
        int f = task >> 6, lane = task & 63;
        int r = lane & 15, kqi = lane >> 4;
        const float* src = emb + (size_t)tok[r] * H_ + f * 32 + kqi * 8;
        bf16 tmp[8];
        #pragma unroll
        for (int e = 0; e < 8; ++e) tmp[e] = __float2bfloat16(src[e]);
        *reinterpret_cast<f32x4*>(base + f * 1024 + lane * 16) =
            *reinterpret_cast<f32x4*>(tmp);
    }
}

// Pack weights fragment-linear with GATE-INTERLEAVED cols:
// wave q's B-col c (=lane&15): gate = c&3, jj = c>>2; W row = gate*512 + s*16 + q*4 + jj
__global__ __launch_bounds__(256) void k_pack(const float* __restrict__ Wih0, const float* __restrict__ Whh0,
                                              const float* __restrict__ Wih1, const float* __restrict__ Whh1,
                                              bf16* __restrict__ Wp) {
    const int s = blockIdx.x, q = blockIdx.y, l = blockIdx.z;
    const float* Wx = l ? Wih1 : Wih0;
    const float* Wh = l ? Whh1 : Whh0;
    bf16* base = Wp + (size_t)(l * 32 + s) * 65536;
    for (int u = threadIdx.x; u < 2048; u += 256) {
        int kc = u >> 6, lane = u & 63;
        int c = lane & 15;
        int row = (c & 3) * H_ + s * 16 + q * 4 + (c >> 2);
        int col = (kc & 15) * 32 + (lane >> 4) * 8;
        const float* src = ((kc < 16) ? Wx : Wh) + (size_t)row * H_ + col;
        bf16* dst = base + ((size_t)(q * 32 + kc) * 64 + lane) * 8;
        #pragma unroll
        for (int e = 0; e < 8; ++e) dst[e] = __float2bfloat16(src[e]);
    }
}

// ---------------- seqlock ring helpers ----------------
// Ring tile per (strip, slot): 1024B = 64 chunks x 16B.
// chunk c = [8B payload: 4 bf16 of row (c&15), col-quarter (c>>4)][4B seq][4B pad].
// Producer dual-stores (sc0 local / sc1 global). Consumer probes, seq-validates.
// RETRY SCHEDULE: rounds 1-3 local-only (cheap L2 RT), rounds >=4 local+global
// with copy-over (wrong-XCD safety net). Never pace the common case on global RT.

#define WAITALL()                                                            \
    asm volatile("s_waitcnt vmcnt(0)" ::: "memory");                         \
    __builtin_amdgcn_sched_barrier(0);

#define ISSUE_CHF(CA, CB, base, SC)                                          \
    _Pragma("unroll")                                                        \
    for (int i = 0; i < 4; ++i) {                                            \
        const char* pa_ = (base) + (2 * (q * 4 + i) + (kqi >> 1)) * 1024     \
                          + (qa * 16 + row) * 16;                            \
        asm volatile("global_load_dwordx4 %0, %2, off" SC "\n\t"             \
                     "global_load_dwordx4 %1, %3, off" SC                    \
                     : "=v"(CA[i]), "=v"(CB[i])                              \
                     : "v"(pa_), "v"(pa_ + 256));                            \
    }

#define CHECK8(CA, CB, sq, okv)                                              \
    { okv = 1;                                                               \
      _Pragma("unroll")                                                      \
      for (int i = 0; i < 4; ++i)                                            \
          okv &= (CA[i].z == (u32)(sq)) & (CB[i].z == (u32)(sq)); }

#define STAGE_CH(CA, CB, fbase)                                              \
    _Pragma("unroll")                                                        \
    for (int i = 0; i < 4; ++i) {                                            \
        u32x4 fr_ = u32x4{CA[i].x, CA[i].y, CB[i].x, CB[i].y};               \
        stagev[(size_t)((fbase) + q * 4 + i) * 64 + lane] =                  \
            __builtin_bit_cast(f32x4, fr_);                                  \
    }

// 16 fragment loads from packed E (contiguous 1KB per fragment), cacheable
#define ISSUE16L(arr, basep)                                                 \
    _Pragma("unroll")                                                        \
    for (int kc = 0; kc < 16; ++kc) {                                        \
        asm volatile("global_load_dwordx4 %0, %1, off"                       \
                     : "=v"(arr[kc]) : "v"((basep) + kc * 1024));            \
    }

// A from registers (l0 x-part from packed E)
#define MFMA16_REG(arr, woff)                                                \
    _Pragma("unroll")                                                        \
    for (int kc = 0; kc < 16; ++kc) {                                        \
        f32x4 wf = wldsv[(size_t)(q * 32 + (woff) + kc) * 64 + lane];        \
        acc[kc & 3] = __builtin_amdgcn_mfma_f32_16x16x32_bf16(               \
            __builtin_bit_cast(bf16x8, arr[kc]),                             \
            __builtin_bit_cast(bf16x8, wf), acc[kc & 3], 0, 0, 0);           \
    }

// A from the LDS stage buffer at fragment offset soff (linear, conflict-free)
#define MFMA16_S(soff, woff)                                                 \
    _Pragma("unroll")                                                        \
    for (int kc = 0; kc < 16; ++kc) {                                        \
        f32x4 af = stagev[(size_t)((soff) + kc) * 64 + lane];                \
        f32x4 wf = wldsv[(size_t)(q * 32 + (woff) + kc) * 64 + lane];        \
        acc[kc & 3] = __builtin_amdgcn_mfma_f32_16x16x32_bf16(               \
            __builtin_bit_cast(bf16x8, af),                                  \
            __builtin_bit_cast(bf16x8, wf), acc[kc & 3], 0, 0, 0);           \
    }

// ---------------- persistent 2-layer LSTM ----------------
// 256 blocks (1/CU, 160KB dyn LDS). block = (g=bid&7 -> (layer,m), strip s=bid>>3).
// r20 structure (seqlock + dual-publish + gate-interleave shuffle exchange).
// ONLY change: retry schedule is local-first (rounds 1-3 local-only) so the
// common-case rendezvous is paced by XCD-L2 RT, not global RT.
__global__ __launch_bounds__(256, 1) void k_lstm(
    const bf16* __restrict__ Wp, const char* __restrict__ Epk,
    const float* __restrict__ bias0, const float* __restrict__ bias1,
    char* __restrict__ h0ring, char* __restrict__ h1ring,
    char* __restrict__ h0loc, char* __restrict__ h1loc,
    int* __restrict__ fx, float* __restrict__ last1, const int* __restrict__ lens)
{
    extern __shared__ char smem[];                 // [0,128K) weights | [128K,160K) stage
    f32x4* wldsv  = (f32x4*)smem;
    f32x4* stagev = (f32x4*)(smem + 131072);

    const int bid   = blockIdx.x;
    const int g     = bid & 7;           // group: layer*4+m
    const int s     = bid >> 3;          // strip 0..31
    const int layer = g >> 2;
    const int m     = g & 3;
    const int tid   = threadIdx.x;
    const int lane  = tid & 63;
    const int q     = tid >> 6;          // wave: j-quarter of the strip
    const int kqi   = lane >> 4;
    const int row   = lane & 15;
    const int qa    = (kqi & 1) * 2;

    // ---- stage this block's 128KB weight slice into LDS ----
    {
        const f32x4* wsrc = (const f32x4*)(Wp + (size_t)(layer * 32 + s) * 65536);
        for (int i = tid; i < 8192; i += 256) wldsv[i] = wsrc[i];
    }

    // ---- elementwise mapping (gate-interleaved): one (b,j) per thread ----
    const int jj    = (lane >> 2) & 3;
    const int b_loc = 4 * (lane >> 4) + (lane & 3);
    const int brow  = m * 16 + b_loc;
    const int jcol  = s * 16 + q * 4 + jj;
    float c_reg = 0.f;
    const float* bias = layer ? bias1 : bias0;
    const float bi0 = bias[0 * H_ + jcol];
    const float bi1 = bias[1 * H_ + jcol];
    const float bi2 = bias[2 * H_ + jcol];
    const float bi3 = bias[3 * H_ + jcol];
    int target = lens[brow] - 1;
    if (target < 0) target = T_ - 1;

    int* flagp = fx + m * 32;                  // l1-progress flag (one dword per m)

    char* grp0 = h0ring + (size_t)m * 8 * 32768;
    char* grp1 = h1ring + (size_t)m * 8 * 32768;
    char* loc0 = h0loc + (size_t)m * 8 * 32768;
    char* loc1 = h1loc + (size_t)m * 8 * 32768;
    char* mygrp = layer ? grp1 : grp0;
    char* myloc = layer ? loc1 : loc0;

    __syncthreads();                           // weights staged

    for (int tt = 0; tt < T_; ++tt) {
        f32x4 acc[4];
        #pragma unroll
        for (int i = 0; i < 4; ++i) acc[i] = f32x4{0.f, 0.f, 0.f, 0.f};
        const int slot_w = tt & 7;
        const int slot_r = (tt - 1) & 7;

        if (layer == 0) {
            // E x-fragments + LOCAL h seqlock probe, one window
            f32x4 xreg[16];
            const char* xp = Epk + ((size_t)(tt * 4 + m)) * 16384 + lane * 16;
            ISSUE16L(xreg, xp)
            const char* hL = loc0 + slot_r * 32768;
            const char* hG = grp0 + slot_r * 32768;
            u32x4 ca[4], cb[4];
            ISSUE_CHF(ca, cb, hL, " sc0")
            WAITALL()
            MFMA16_REG(xreg, 0)                 // x-compute while h may retry
            int ok; CHECK8(ca, cb, tt, ok)
            int gd = 0;
            while (!__all(ok)) {
                if (++gd > (1 << 16)) break;
                if (gd <= 3) {
                    // cheap local-only retry round (XCD-L2 RT)
                    ISSUE_CHF(ca, cb, hL, " sc0")
                    WAITALL()
                    CHECK8(ca, cb, tt, ok)
                } else {
                    // safety net: local + global, accept whichever validates
                    u32x4 ga[4], gb[4];
                    ISSUE_CHF(ca, cb, hL, " sc0")
                    ISSUE_CHF(ga, gb, hG, " sc0 sc1")
                    WAITALL()
                    CHECK8(ca, cb, tt, ok)
                    if (!__all(ok)) {
                        int ok2; CHECK8(ga, gb, tt, ok2)
                        if (__all(ok2)) {
                            #pragma unroll
                            for (int i = 0; i < 4; ++i) { ca[i] = ga[i]; cb[i] = gb[i]; }
                            ok = 1;
                        }
                    }
                }
            }
            __builtin_amdgcn_sched_barrier(0);
            __syncthreads();                    // pre-stage: prev-iter stage reads done
            STAGE_CH(ca, cb, 0)
            __syncthreads();                    // stage ready
            MFMA16_S(0, 16)
        } else {
            // x (l0 step tt, seq tt+1) global; h (own, seq tt) LOCAL-first
            const char* xG = grp0 + slot_w * 32768;
            const char* hL = loc1 + slot_r * 32768;
            const char* hG = grp1 + slot_r * 32768;
            u32x4 xa[4], xb[4], ha[4], hb[4];
            ISSUE_CHF(ha, hb, hL, " sc0")
            ISSUE_CHF(xa, xb, xG, " sc0 sc1")
            WAITALL()
            int okx, okh;
            CHECK8(xa, xb, tt + 1, okx)
            CHECK8(ha, hb, tt, okh)
            int gd = 0;
            while (!__all(okx & okh)) {
                if (++gd > (1 << 16)) break;
                if (!__all(okh)) {
                    if (gd <= 3) {
                        // cheap local-only retry round for h
                        ISSUE_CHF(ha, hb, hL, " sc0")
                        WAITALL()
                        CHECK8(ha, hb, tt, okh)
                    } else {
                        u32x4 ga[4], gb[4];
                        ISSUE_CHF(ha, hb, hL, " sc0")
                        ISSUE_CHF(ga, gb, hG, " sc0 sc1")
                        WAITALL()
                        CHECK8(ha, hb, tt, okh)
                        if (!__all(okh)) {
                            int ok2; CHECK8(ga, gb, tt, ok2)
                            if (__all(ok2)) {
                                #pragma unroll
                                for (int i = 0; i < 4; ++i) { ha[i] = ga[i]; hb[i] = gb[i]; }
                                okh = 1;
                            }
                        }
                    }
                }
                if (!__all(okx)) {
                    ISSUE_CHF(xa, xb, xG, " sc0 sc1")
                    WAITALL()
                    CHECK8(xa, xb, tt + 1, okx)
                }
            }
            __builtin_amdgcn_sched_barrier(0);
            __syncthreads();                    // pre-stage: prev-iter stage reads done
            STAGE_CH(xa, xb, 0)
            STAGE_CH(ha, hb, 16)
            __syncthreads();                    // stage ready
            if (tid == 0) {                     // publish x-ring consumption
                int fv = tt + 1;
                asm volatile("global_store_dword %0, %1, off sc0 sc1" :: "v"(flagp), "v"(fv) : "memory");
            }
            MFMA16_S(0, 0)
            MFMA16_S(16, 16)
        }

        f32x4 v = (acc[0] + acc[1]) + (acc[2] + acc[3]);

        // ---- quad 4x4 transpose (lane&3 = gate): 8 shfl + selects ----
        float r0 = __shfl_xor(v.x, 1), r1 = __shfl_xor(v.y, 1),
              r2 = __shfl_xor(v.z, 1), r3 = __shfl_xor(v.w, 1);
        const bool oddl = (lane & 1) != 0;
        float n0 = oddl ? r1 : v.x;
        float n1 = oddl ? v.y : r0;
        float n2 = oddl ? r3 : v.z;
        float n3 = oddl ? v.w : r2;
        float s0 = __shfl_xor(n0, 2), s1 = __shfl_xor(n1, 2),
              s2 = __shfl_xor(n2, 2), s3 = __shfl_xor(n3, 2);
        const bool hil = (lane & 2) != 0;
        float mi = hil ? s2 : n0;
        float mf = hil ? s3 : n1;
        float mg = hil ? n2 : s0;
        float mo = hil ? n3 : s1;

        // ---- elementwise LSTM update (per-thread (b,j)) ----
        float gi = sigmoidf_(mi + bi0);
        float gf = sigmoidf_(mf + bi1);
        float gg = tanhf_  (mg + bi2);
        float go = sigmoidf_(mo + bi3);
        c_reg = gf * c_reg + gi * gg;
        float hn = go * tanhf_(c_reg);
        if (layer == 1 && tt == target)
            last1[(size_t)brow * H_ + jcol] = hn;

        // ---- l0 ring pacing: l1 must have consumed slot tt-8 ----
        if (layer == 0 && tid < 64 && tt >= 8) {
            int gd2 = 0;
            while (true) {
                int vfl;
                asm volatile("global_load_dword %0, %1, off sc0 sc1\n\ts_waitcnt vmcnt(0)"
                             : "=v"(vfl) : "v"(flagp) : "memory");
                if (vfl >= tt - 7) break;
                if (++gd2 > (1 << 16)) break;
                __builtin_amdgcn_s_sleep(2);
            }
            __builtin_amdgcn_sched_barrier(0);
        }

        // ---- pack (2 shfl) + dual seqlock store: wave q stores chunks q*16+b ----
        {
            bf16 hb16 = __float2bfloat16(hn);
            u32 hw = (u32)__builtin_bit_cast(unsigned short, hb16);
            u32 p1 = __shfl_xor(hw, 4);
            u32 w  = (hw & 0xffffu) | (p1 << 16);       // valid on even-jj lanes
            u32 w2 = __shfl_xor(w, 8);
            if ((lane & 12) == 0) {
                u32x4 ch = u32x4{w, w2, (u32)(tt + 1), 0u};
                f32x4 chv = __builtin_bit_cast(f32x4, ch);
                size_t off = (size_t)slot_w * 32768 + s * 1024 + (q * 16 + b_loc) * 16;
                asm volatile("global_store_dwordx4 %0, %1, off sc0"
                             :: "v"(myloc + off), "v"(chv) : "memory");
                asm volatile("global_store_dwordx4 %0, %1, off sc0 sc1"
                             :: "v"(mygrp + off), "v"(chv) : "memory");
            }
        }
    }
}

// out[b][tag] = last1[b] . Wout[tag] + bout[tag]   (fp32)
__global__ __launch_bounds__(64) void k_out(const float* __restrict__ last1,
                                            const float* __restrict__ Wout,
                                            const float* __restrict__ bout,
                                            float* __restrict__ out) {
    int b = blockIdx.x, tg = blockIdx.y, lane = threadIdx.x;
    float sum = 0.f;
    for (int d = lane; d < H_; d += 64)
        sum += last1[(size_t)b * H_ + d] * Wout[(size_t)tg * H_ + d];
    #pragma unroll
    for (int off = 32; off; off >>= 1) sum += __shfl_xor(sum, off);
    if (lane == 0) out[b * TAGS_ + tg] = sum + bout[tg];
}

// ---------------- host ----------------

extern "C" void kernel_launch(void* const* d_in, const int* in_sizes, int n_in,
                              void* d_out, int out_size, void* d_ws, size_t ws_size,
                              hipStream_t stream)
{
    const int*   x    = (const int*)  d_in[0];
    const float* emb  = (const float*)d_in[1];
    const float* Wih0 = (const float*)d_in[2];
    const float* Whh0 = (const float*)d_in[3];
    const float* bih0 = (const float*)d_in[4];
    const float* bhh0 = (const float*)d_in[5];
    const float* Wih1 = (const float*)d_in[6];
    const float* Whh1 = (const float*)d_in[7];
    const float* bih1 = (const float*)d_in[8];
    const float* bhh1 = (const float*)d_in[9];
    const float* Wout = (const float*)d_in[10];
    const float* bout = (const float*)d_in[11];
    float* out = (float*)d_out;

    char* p = (char*)d_ws;
    char* Epk  = p;         p += (size_t)T_ * 4 * 16384;        // 32 MB packed E
    bf16* Wp   = (bf16*)p;  p += (size_t)2 * 32 * 65536 * 2;    // 8 MB packed weights
    float* bias0 = (float*)p; p += (size_t)G_ * 4;
    float* bias1 = (float*)p; p += (size_t)G_ * 4;
    char* zbase = p;                                            // zeroed every launch
    char* h0ring = p; p += (size_t)4 * 8 * 32768;               // 1 MB seqlock ring (global)
    char* h1ring = p; p += (size_t)4 * 8 * 32768;               // 1 MB seqlock ring (global)
    char* h0loc  = p; p += (size_t)4 * 8 * 32768;               // 1 MB local (XCD-L2) ring
    char* h1loc  = p; p += (size_t)4 * 8 * 32768;               // 1 MB local (XCD-L2) ring
    int*  fx     = (int*)p;  p += 8 * 32 * 4;                   // l1 progress flags
    size_t zbytes = (size_t)(p - zbase);
    float* last1 = (float*)p; p += (size_t)B_ * H_ * 4;
    int* lens = (int*)p; p += 256;

    (void)hipFuncSetAttribute((const void*)k_lstm,
                              hipFuncAttributeMaxDynamicSharedMemorySize, 163840);

    k_zero<<<dim3(128), dim3(256), 0, stream>>>((uint32_t*)zbase, (int)(zbytes / 4));
    k_lens<<<dim3(B_), dim3(256), 0, stream>>>(x, lens);
    k_addb<<<dim3(8), dim3(256), 0, stream>>>(bih0, bhh0, bias0, G_);
    k_addb<<<dim3(8), dim3(256), 0, stream>>>(bih1, bhh1, bias1, G_);
    k_pack<<<dim3(32, 4, 2), dim3(256), 0, stream>>>(Wih0, Whh0, Wih1, Whh1, Wp);
    k_gather<<<dim3(T_, 4), dim3(256), 0, stream>>>(x, emb, Epk);

    k_lstm<<<dim3(256), dim3(256), 163840, stream>>>(Wp, Epk, bias0, bias1,
                                                     h0ring, h1ring, h0loc, h1loc,
                                                     fx, last1, lens);

    k_out<<<dim3(B_, TAGS_), dim3(64), 0, stream>>>(last1, Wout, bout, out);
}

// Round 22
// 1461.860 us; speedup vs baseline: 374.1038x; 374.1038x over previous
//
#include <hip/hip_runtime.h>
#include <hip/hip_bf16.h>
#include <stdint.h>

#define B_    64
#define T_    512
#define H_    512
#define G_    2048    // 4*H
#define TAGS_ 20

typedef __hip_bfloat16 bf16;
typedef __bf16 bf16x8 __attribute__((ext_vector_type(8)));
typedef float  f32x4  __attribute__((ext_vector_type(4)));
typedef unsigned int u32;
typedef u32 u32x4 __attribute__((ext_vector_type(4)));
typedef u32 u32x2 __attribute__((ext_vector_type(2)));

__device__ __forceinline__ float sigmoidf_(float x) { return 1.0f / (1.0f + __expf(-x)); }
__device__ __forceinline__ float tanhf_(float x)    { return 1.0f - 2.0f / (__expf(2.0f * x) + 1.0f); }

// ---------------- prep kernels ----------------

__global__ void k_zero(uint32_t* __restrict__ p, int n) {
    for (int i = blockIdx.x * blockDim.x + threadIdx.x; i < n; i += gridDim.x * blockDim.x)
        p[i] = 0u;
}

__global__ void k_addb(const float* __restrict__ a, const float* __restrict__ b,
                       float* __restrict__ o, int n) {
    for (int i = blockIdx.x * blockDim.x + threadIdx.x; i < n; i += gridDim.x * blockDim.x)
        o[i] = a[i] + b[i];
}

__global__ __launch_bounds__(256) void k_lens(const int* __restrict__ x, int* __restrict__ lens) {
    int b = blockIdx.x;
    int cnt = 0;
    for (int tpos = threadIdx.x; tpos < T_; tpos += 256)
        cnt += (x[(size_t)b * T_ + tpos] == 0) ? 1 : 0;
    #pragma unroll
    for (int off = 32; off; off >>= 1) cnt += __shfl_xor(cnt, off);
    __shared__ int tot;
    if (threadIdx.x == 0) tot = 0;
    __syncthreads();
    if ((threadIdx.x & 63) == 0) atomicAdd(&tot, cnt);
    __syncthreads();
    if (threadIdx.x == 0) lens[b] = T_ - tot;
}

// E packed fragment-linear: Epk[(t*4+m)*16KB + f*1024 + lane*16] =
//   bf16x8 of emb[x[m*16+(lane&15)][t]][f*32+(lane>>4)*8 .. +8]
__global__ __launch_bounds__(256) void k_gather(const int* __restrict__ x,
                                                const float* __restrict__ emb,
                                                char* __restrict__ Epk) {
    const int t = blockIdx.x, m = blockIdx.y;
    __shared__ int tok[16];
    if (threadIdx.x < 16) tok[threadIdx.x] = x[(size_t)(m * 16 + threadIdx.x) * T_ + t];
    __syncthreads();
    char* base = Epk + ((size_t)(t * 4 + m)) * 16384;
    for (int task = threadIdx.x; task < 1024; task += 256) {
        int f = task >> 6, lane = task & 63;
        int r = lane & 15, kqi = lane >> 4;
        const float* src = emb + (size_t)tok[r] * H_ + f * 32 + kqi * 8;
        bf16 tmp[8];
        #pragma unroll
        for (int e = 0; e < 8; ++e) tmp[e] = __float2bfloat16(src[e]);
        *reinterpret_cast<f32x4*>(base + f * 1024 + lane * 16) =
            *reinterpret_cast<f32x4*>(tmp);
    }
}

// Pack weights fragment-linear with GATE-INTERLEAVED cols:
// wave q's B-col c (=lane&15): gate = c&3, jj = c>>2; W row = gate*512 + s*16 + q*4 + jj
__global__ __launch_bounds__(256) void k_pack(const float* __restrict__ Wih0, const float* __restrict__ Whh0,
                                              const float* __restrict__ Wih1, const float* __restrict__ Whh1,
                                              bf16* __restrict__ Wp) {
    const int s = blockIdx.x, q = blockIdx.y, l = blockIdx.z;
    const float* Wx = l ? Wih1 : Wih0;
    const float* Wh = l ? Whh1 : Whh0;
    bf16* base = Wp + (size_t)(l * 32 + s) * 65536;
    for (int u = threadIdx.x; u < 2048; u += 256) {
        int kc = u >> 6, lane = u & 63;
        int c = lane & 15;
        int row = (c & 3) * H_ + s * 16 + q * 4 + (c >> 2);
        int col = (kc & 15) * 32 + (lane >> 4) * 8;
        const float* src = ((kc < 16) ? Wx : Wh) + (size_t)row * H_ + col;
        bf16* dst = base + ((size_t)(q * 32 + kc) * 64 + lane) * 8;
        #pragma unroll
        for (int e = 0; e < 8; ++e) dst[e] = __float2bfloat16(src[e]);
    }
}

// ---------------- seqlock ring helpers (r18-proven) ----------------
// Ring tile per (strip, slot): 1024B = 64 chunks x 16B.
// chunk c = [8B payload: 4 bf16 of row (c&15), col-quarter (c>>4)][4B seq][4B pad].
// Producer dual-stores (sc0 local / sc1 global). Consumer probes, seq-validates.
// Retry rounds ALWAYS include the sc0 sc1 (bypass-all) loads — that is the
// guaranteed-progress mechanism (r21's local-only retries livelocked).

#define WAITALL()                                                            \
    asm volatile("s_waitcnt vmcnt(0)" ::: "memory");                         \
    __builtin_amdgcn_sched_barrier(0);

#define ISSUE_CHF(CA, CB, base, SC)                                          \
    _Pragma("unroll")                                                        \
    for (int i = 0; i < 4; ++i) {                                            \
        const char* pa_ = (base) + (2 * (q * 4 + i) + (kqi >> 1)) * 1024     \
                          + (qa * 16 + row) * 16;                            \
        asm volatile("global_load_dwordx4 %0, %2, off" SC "\n\t"             \
                     "global_load_dwordx4 %1, %3, off" SC                    \
                     : "=v"(CA[i]), "=v"(CB[i])                              \
                     : "v"(pa_), "v"(pa_ + 256));                            \
    }

#define CHECK8(CA, CB, sq, okv)                                              \
    { okv = 1;                                                               \
      _Pragma("unroll")                                                      \
      for (int i = 0; i < 4; ++i)                                            \
          okv &= (CA[i].z == (u32)(sq)) & (CB[i].z == (u32)(sq)); }

#define STAGE_CH(CA, CB, fbase)                                              \
    _Pragma("unroll")                                                        \
    for (int i = 0; i < 4; ++i) {                                            \
        u32x4 fr_ = u32x4{CA[i].x, CA[i].y, CB[i].x, CB[i].y};               \
        stagev[(size_t)((fbase) + q * 4 + i) * 64 + lane] =                  \
            __builtin_bit_cast(f32x4, fr_);                                  \
    }

// 16 fragment loads from packed E (contiguous 1KB per fragment), cacheable
#define ISSUE16L(arr, basep)                                                 \
    _Pragma("unroll")                                                        \
    for (int kc = 0; kc < 16; ++kc) {                                        \
        asm volatile("global_load_dwordx4 %0, %1, off"                       \
                     : "=v"(arr[kc]) : "v"((basep) + kc * 1024));            \
    }

// A from registers (l0 x-part from packed E)
#define MFMA16_REG(arr, woff)                                                \
    _Pragma("unroll")                                                        \
    for (int kc = 0; kc < 16; ++kc) {                                        \
        f32x4 wf = wldsv[(size_t)(q * 32 + (woff) + kc) * 64 + lane];        \
        acc[kc & 3] = __builtin_amdgcn_mfma_f32_16x16x32_bf16(               \
            __builtin_bit_cast(bf16x8, arr[kc]),                             \
            __builtin_bit_cast(bf16x8, wf), acc[kc & 3], 0, 0, 0);           \
    }

// A from the LDS stage buffer at fragment offset soff (linear, conflict-free)
#define MFMA16_S(soff, woff)                                                 \
    _Pragma("unroll")                                                        \
    for (int kc = 0; kc < 16; ++kc) {                                        \
        f32x4 af = stagev[(size_t)((soff) + kc) * 64 + lane];                \
        f32x4 wf = wldsv[(size_t)(q * 32 + (woff) + kc) * 64 + lane];        \
        acc[kc & 3] = __builtin_amdgcn_mfma_f32_16x16x32_bf16(               \
            __builtin_bit_cast(bf16x8, af),                                  \
            __builtin_bit_cast(bf16x8, wf), acc[kc & 3], 0, 0, 0);           \
    }

// ---------------- persistent 2-layer LSTM ----------------
// 256 blocks (1/CU, 160KB dyn LDS). block = (g=bid&7 -> (layer,m), strip s=bid>>3).
// r18 seqlock + dual-publish + full-reload retries (proven). Gate-interleaved
// MFMA cols -> 4 gates of a (b,j) in one lane-quad -> 8-shfl quad transpose
// replaces the LDS gate exchange; 2 barriers/step (pre-stage, stage-ready).
__global__ __launch_bounds__(256, 1) void k_lstm(
    const bf16* __restrict__ Wp, const char* __restrict__ Epk,
    const float* __restrict__ bias0, const float* __restrict__ bias1,
    char* __restrict__ h0ring, char* __restrict__ h1ring,
    char* __restrict__ h0loc, char* __restrict__ h1loc,
    int* __restrict__ fx, float* __restrict__ last1, const int* __restrict__ lens)
{
    extern __shared__ char smem[];                 // [0,128K) weights | [128K,160K) stage
    f32x4* wldsv  = (f32x4*)smem;
    f32x4* stagev = (f32x4*)(smem + 131072);

    const int bid   = blockIdx.x;
    const int g     = bid & 7;           // group: layer*4+m
    const int s     = bid >> 3;          // strip 0..31
    const int layer = g >> 2;
    const int m     = g & 3;
    const int tid   = threadIdx.x;
    const int lane  = tid & 63;
    const int q     = tid >> 6;          // wave: j-quarter of the strip
    const int kqi   = lane >> 4;
    const int row   = lane & 15;
    const int qa    = (kqi & 1) * 2;

    // ---- stage this block's 128KB weight slice into LDS ----
    {
        const f32x4* wsrc = (const f32x4*)(Wp + (size_t)(layer * 32 + s) * 65536);
        for (int i = tid; i < 8192; i += 256) wldsv[i] = wsrc[i];
    }

    // ---- elementwise mapping (gate-interleaved): one (b,j) per thread ----
    const int jj    = (lane >> 2) & 3;
    const int b_loc = 4 * (lane >> 4) + (lane & 3);
    const int brow  = m * 16 + b_loc;
    const int jcol  = s * 16 + q * 4 + jj;
    float c_reg = 0.f;
    const float* bias = layer ? bias1 : bias0;
    const float bi0 = bias[0 * H_ + jcol];
    const float bi1 = bias[1 * H_ + jcol];
    const float bi2 = bias[2 * H_ + jcol];
    const float bi3 = bias[3 * H_ + jcol];
    int target = lens[brow] - 1;
    if (target < 0) target = T_ - 1;

    int* flagp = fx + m * 32;                  // l1-progress flag (one dword per m)

    char* grp0 = h0ring + (size_t)m * 8 * 32768;
    char* grp1 = h1ring + (size_t)m * 8 * 32768;
    char* loc0 = h0loc + (size_t)m * 8 * 32768;
    char* loc1 = h1loc + (size_t)m * 8 * 32768;
    char* mygrp = layer ? grp1 : grp0;
    char* myloc = layer ? loc1 : loc0;

    __syncthreads();                           // weights staged

    for (int tt = 0; tt < T_; ++tt) {
        f32x4 acc[4];
        #pragma unroll
        for (int i = 0; i < 4; ++i) acc[i] = f32x4{0.f, 0.f, 0.f, 0.f};
        const int slot_w = tt & 7;
        const int slot_r = (tt - 1) & 7;

        if (layer == 0) {
            // E x-fragments + LOCAL h seqlock probe, one window
            f32x4 xreg[16];
            const char* xp = Epk + ((size_t)(tt * 4 + m)) * 16384 + lane * 16;
            ISSUE16L(xreg, xp)
            const char* hL = loc0 + slot_r * 32768;
            const char* hG = grp0 + slot_r * 32768;
            u32x4 ca[4], cb[4];
            ISSUE_CHF(ca, cb, hL, " sc0")
            WAITALL()
            MFMA16_REG(xreg, 0)                 // x-compute while h may retry
            int ok; CHECK8(ca, cb, tt, ok)
            int gd = 0;
            while (!__all(ok)) {
                if (++gd > (1 << 16)) break;
                u32x4 ga[4], gb[4];
                ISSUE_CHF(ca, cb, hL, " sc0")
                ISSUE_CHF(ga, gb, hG, " sc0 sc1")
                WAITALL()
                CHECK8(ca, cb, tt, ok)
                if (!__all(ok)) {
                    int ok2; CHECK8(ga, gb, tt, ok2)
                    if (__all(ok2)) {
                        #pragma unroll
                        for (int i = 0; i < 4; ++i) { ca[i] = ga[i]; cb[i] = gb[i]; }
                        ok = 1;
                    }
                }
            }
            __builtin_amdgcn_sched_barrier(0);
            __syncthreads();                    // pre-stage: prev-iter stage reads done
            STAGE_CH(ca, cb, 0)
            __syncthreads();                    // stage ready
            MFMA16_S(0, 16)
        } else {
            // x (l0 step tt, seq tt+1) global; h (own, seq tt) LOCAL-first
            const char* xG = grp0 + slot_w * 32768;
            const char* hL = loc1 + slot_r * 32768;
            const char* hG = grp1 + slot_r * 32768;
            u32x4 xa[4], xb[4], ha[4], hb[4];
            ISSUE_CHF(ha, hb, hL, " sc0")
            ISSUE_CHF(xa, xb, xG, " sc0 sc1")
            WAITALL()
            int okx, okh;
            CHECK8(xa, xb, tt + 1, okx)
            CHECK8(ha, hb, tt, okh)
            int gd = 0;
            while (!__all(okx & okh)) {
                if (++gd > (1 << 16)) break;
                if (!__all(okh)) {
                    u32x4 ga[4], gb[4];
                    ISSUE_CHF(ha, hb, hL, " sc0")
                    ISSUE_CHF(ga, gb, hG, " sc0 sc1")
                    WAITALL()
                    CHECK8(ha, hb, tt, okh)
                    if (!__all(okh)) {
                        int ok2; CHECK8(ga, gb, tt, ok2)
                        if (__all(ok2)) {
                            #pragma unroll
                            for (int i = 0; i < 4; ++i) { ha[i] = ga[i]; hb[i] = gb[i]; }
                            okh = 1;
                        }
                    }
                }
                if (!__all(okx)) {
                    ISSUE_CHF(xa, xb, xG, " sc0 sc1")
                    WAITALL()
                    CHECK8(xa, xb, tt + 1, okx)
                }
            }
            __builtin_amdgcn_sched_barrier(0);
            __syncthreads();                    // pre-stage: prev-iter stage reads done
            STAGE_CH(xa, xb, 0)
            STAGE_CH(ha, hb, 16)
            __syncthreads();                    // stage ready
            if (tid == 0) {                     // publish x-ring consumption
                int fv = tt + 1;
                asm volatile("global_store_dword %0, %1, off sc0 sc1" :: "v"(flagp), "v"(fv) : "memory");
            }
            MFMA16_S(0, 0)
            MFMA16_S(16, 16)
        }

        f32x4 v = (acc[0] + acc[1]) + (acc[2] + acc[3]);

        // ---- quad 4x4 transpose (lane&3 = gate): 8 shfl + selects ----
        float r0 = __shfl_xor(v.x, 1), r1 = __shfl_xor(v.y, 1),
              r2 = __shfl_xor(v.z, 1), r3 = __shfl_xor(v.w, 1);
        const bool oddl = (lane & 1) != 0;
        float n0 = oddl ? r1 : v.x;
        float n1 = oddl ? v.y : r0;
        float n2 = oddl ? r3 : v.z;
        float n3 = oddl ? v.w : r2;
        float s0 = __shfl_xor(n0, 2), s1 = __shfl_xor(n1, 2),
              s2 = __shfl_xor(n2, 2), s3 = __shfl_xor(n3, 2);
        const bool hil = (lane & 2) != 0;
        float mi = hil ? s2 : n0;
        float mf = hil ? s3 : n1;
        float mg = hil ? n2 : s0;
        float mo = hil ? n3 : s1;

        // ---- elementwise LSTM update (per-thread (b,j)) ----
        float gi = sigmoidf_(mi + bi0);
        float gf = sigmoidf_(mf + bi1);
        float gg = tanhf_  (mg + bi2);
        float go = sigmoidf_(mo + bi3);
        c_reg = gf * c_reg + gi * gg;
        float hn = go * tanhf_(c_reg);
        if (layer == 1 && tt == target)
            last1[(size_t)brow * H_ + jcol] = hn;

        // ---- l0 ring pacing: l1 must have consumed slot tt-8 ----
        if (layer == 0 && tid < 64 && tt >= 8) {
            int gd2 = 0;
            while (true) {
                int vfl;
                asm volatile("global_load_dword %0, %1, off sc0 sc1\n\ts_waitcnt vmcnt(0)"
                             : "=v"(vfl) : "v"(flagp) : "memory");
                if (vfl >= tt - 7) break;
                if (++gd2 > (1 << 16)) break;
                __builtin_amdgcn_s_sleep(2);
            }
            __builtin_amdgcn_sched_barrier(0);
        }

        // ---- pack (2 shfl) + dual seqlock store: wave q stores chunks q*16+b ----
        {
            bf16 hb16 = __float2bfloat16(hn);
            u32 hw = (u32)__builtin_bit_cast(unsigned short, hb16);
            u32 p1 = __shfl_xor(hw, 4);
            u32 w  = (hw & 0xffffu) | (p1 << 16);       // valid on even-jj lanes
            u32 w2 = __shfl_xor(w, 8);
            if ((lane & 12) == 0) {
                u32x4 ch = u32x4{w, w2, (u32)(tt + 1), 0u};
                f32x4 chv = __builtin_bit_cast(f32x4, ch);
                size_t off = (size_t)slot_w * 32768 + s * 1024 + (q * 16 + b_loc) * 16;
                asm volatile("global_store_dwordx4 %0, %1, off sc0"
                             :: "v"(myloc + off), "v"(chv) : "memory");
                asm volatile("global_store_dwordx4 %0, %1, off sc0 sc1"
                             :: "v"(mygrp + off), "v"(chv) : "memory");
            }
        }
    }
}

// out[b][tag] = last1[b] . Wout[tag] + bout[tag]   (fp32)
__global__ __launch_bounds__(64) void k_out(const float* __restrict__ last1,
                                            const float* __restrict__ Wout,
                                            const float* __restrict__ bout,
                                            float* __restrict__ out) {
    int b = blockIdx.x, tg = blockIdx.y, lane = threadIdx.x;
    float sum = 0.f;
    for (int d = lane; d < H_; d += 64)
        sum += last1[(size_t)b * H_ + d] * Wout[(size_t)tg * H_ + d];
    #pragma unroll
    for (int off = 32; off; off >>= 1) sum += __shfl_xor(sum, off);
    if (lane == 0) out[b * TAGS_ + tg] = sum + bout[tg];
}

// ---------------- host ----------------

extern "C" void kernel_launch(void* const* d_in, const int* in_sizes, int n_in,
                              void* d_out, int out_size, void* d_ws, size_t ws_size,
                              hipStream_t stream)
{
    const int*   x    = (const int*)  d_in[0];
    const float* emb  = (const float*)d_in[1];
    const float* Wih0 = (const float*)d_in[2];
    const float* Whh0 = (const float*)d_in[3];
    const float* bih0 = (const float*)d_in[4];
    const float* bhh0 = (const float*)d_in[5];
    const float* Wih1 = (const float*)d_in[6];
    const float* Whh1 = (const float*)d_in[7];
    const float* bih1 = (const float*)d_in[8];
    const float* bhh1 = (const float*)d_in[9];
    const float* Wout = (const float*)d_in[10];
    const float* bout = (const float*)d_in[11];
    float* out = (float*)d_out;

    char* p = (char*)d_ws;
    char* Epk  = p;         p += (size_t)T_ * 4 * 16384;        // 32 MB packed E
    bf16* Wp   = (bf16*)p;  p += (size_t)2 * 32 * 65536 * 2;    // 8 MB packed weights
    float* bias0 = (float*)p; p += (size_t)G_ * 4;
    float* bias1 = (float*)p; p += (size_t)G_ * 4;
    char* zbase = p;                                            // zeroed every launch
    char* h0ring = p; p += (size_t)4 * 8 * 32768;               // 1 MB seqlock ring (global)
    char* h1ring = p; p += (size_t)4 * 8 * 32768;               // 1 MB seqlock ring (global)
    char* h0loc  = p; p += (size_t)4 * 8 * 32768;               // 1 MB local (XCD-L2) ring
    char* h1loc  = p; p += (size_t)4 * 8 * 32768;               // 1 MB local (XCD-L2) ring
    int*  fx     = (int*)p;  p += 8 * 32 * 4;                   // l1 progress flags
    size_t zbytes = (size_t)(p - zbase);
    float* last1 = (float*)p; p += (size_t)B_ * H_ * 4;
    int* lens = (int*)p; p += 256;

    (void)hipFuncSetAttribute((const void*)k_lstm,
                              hipFuncAttributeMaxDynamicSharedMemorySize, 163840);

    k_zero<<<dim3(128), dim3(256), 0, stream>>>((uint32_t*)zbase, (int)(zbytes / 4));
    k_lens<<<dim3(B_), dim3(256), 0, stream>>>(x, lens);
    k_addb<<<dim3(8), dim3(256), 0, stream>>>(bih0, bhh0, bias0, G_);
    k_addb<<<dim3(8), dim3(256), 0, stream>>>(bih1, bhh1, bias1, G_);
    k_pack<<<dim3(32, 4, 2), dim3(256), 0, stream>>>(Wih0, Whh0, Wih1, Whh1, Wp);
    k_gather<<<dim3(T_, 4), dim3(256), 0, stream>>>(x, emb, Epk);

    k_lstm<<<dim3(256), dim3(256), 163840, stream>>>(Wp, Epk, bias0, bias1,
                                                     h0ring, h1ring, h0loc, h1loc,
                                                     fx, last1, lens);

    k_out<<<dim3(B_, TAGS_), dim3(64), 0, stream>>>(last1, Wout, bout, out);
}